// Round 1
// baseline (371.819 us; speedup 1.0000x reference)
//
#include <hip/hip_runtime.h>

#define FF 64
#define DD 256
#define NPAIR 2016   // 64*63/2

typedef __attribute__((ext_vector_type(8))) short short8;
typedef __attribute__((ext_vector_type(16))) float f32x16;

// two fp32 -> packed bf16x2, round-to-nearest-even (same numerics as verified kernel)
__device__ __forceinline__ unsigned int pack2(float lo, float hi) {
    unsigned int a = __float_as_uint(lo);
    unsigned int b = __float_as_uint(hi);
    a += 0x7FFFu + ((a >> 16) & 1u);
    b += 0x7FFFu + ((b >> 16) & 1u);
    return (a >> 16) | (b & 0xFFFF0000u);
}

// two float4 (8 consecutive fp32 along k) -> one 8-lane bf16 MFMA fragment
__device__ __forceinline__ short8 mkfrag(float4 a, float4 b) {
    union { unsigned int u[4]; short8 s; } c;
    c.u[0] = pack2(a.x, a.y);
    c.u[1] = pack2(a.z, a.w);
    c.u[2] = pack2(b.x, b.y);
    c.u[3] = pack2(b.z, b.w);
    return c.s;
}

// Wave-autonomous: one wave per batch row, zero LDS, zero barriers.
// A/B fragment layout for mfma_32x32x16_bf16: row(col)=lane&31, k=(lane>>5)*8+j
// -> build fragments straight from global: lane&31 selects the field row,
//    (lane>>5) selects the k-octet. Lanes l and l+32 + the 4 loads per half
//    cover each 128B line exactly once per round (MSHR-merged).
__global__ __launch_bounds__(256, 3) void gram_tri(const float* __restrict__ x,
                                                   float* __restrict__ out) {
    const int t = threadIdx.x;
    const int wave = t >> 6;
    const int lane = t & 63;
    const int b = blockIdx.x * 4 + wave;

    const float4* __restrict__ src = (const float4*)(x + (size_t)b * (FF * DD));
    const int klo = (lane >> 5) << 1;                       // float4 offset of this lane's k-octet
    const float4* __restrict__ p0 = src + (lane & 31) * (DD / 4) + klo;   // field rows 0..31
    const float4* __restrict__ p1 = p0 + 32 * (DD / 4);                   // field rows 32..63

    f32x16 a00, a01, a11;
#pragma unroll
    for (int i = 0; i < 16; ++i) { a00[i] = 0.0f; a01[i] = 0.0f; a11[i] = 0.0f; }

    float4 s0a, s0b, s0c, s0d, s1a, s1b, s1c, s1d;
    // prologue: round 0 loads (round = 32 k-elems = 2 MFMA k-steps; 8 rounds cover D=256)
    s0a = p0[0]; s0b = p0[1]; s0c = p0[4]; s0d = p0[5];
    s1a = p1[0]; s1b = p1[1]; s1c = p1[4]; s1d = p1[5];

#pragma unroll
    for (int r = 0; r < 8; ++r) {
        // convert current round (implicit vmcnt wait; HBM stays saturated via
        // the other resident waves' in-flight loads)
        short8 f0k0 = mkfrag(s0a, s0b);
        short8 f0k1 = mkfrag(s0c, s0d);
        short8 f1k0 = mkfrag(s1a, s1b);
        short8 f1k1 = mkfrag(s1c, s1d);
        // issue next round's loads so they fly during the MFMAs
        if (r < 7) {
            const float4* __restrict__ q0 = p0 + (r + 1) * 8;
            const float4* __restrict__ q1 = p1 + (r + 1) * 8;
            s0a = q0[0]; s0b = q0[1]; s0c = q0[4]; s0d = q0[5];
            s1a = q1[0]; s1b = q1[1]; s1c = q1[4]; s1d = q1[5];
        }
        // three quadrants; diagonal ones reuse the same fragment for A and B
        a00 = __builtin_amdgcn_mfma_f32_32x32x16_bf16(f0k0, f0k0, a00, 0, 0, 0);
        a01 = __builtin_amdgcn_mfma_f32_32x32x16_bf16(f0k0, f1k0, a01, 0, 0, 0);
        a11 = __builtin_amdgcn_mfma_f32_32x32x16_bf16(f1k0, f1k0, a11, 0, 0, 0);
        a00 = __builtin_amdgcn_mfma_f32_32x32x16_bf16(f0k1, f0k1, a00, 0, 0, 0);
        a01 = __builtin_amdgcn_mfma_f32_32x32x16_bf16(f0k1, f1k1, a01, 0, 0, 0);
        a11 = __builtin_amdgcn_mfma_f32_32x32x16_bf16(f1k1, f1k1, a11, 0, 0, 0);
    }

    // epilogue: C/D layout (m74/m101): col=lane&31, row=(reg&3)+8*(reg>>2)+4*(lane>>5)
    float* __restrict__ ob = out + (size_t)b * NPAIR;
    const int jc = lane & 31;
    const int rbase = (lane >> 5) << 2;
#pragma unroll
    for (int reg = 0; reg < 16; ++reg) {
        const int ii = (reg & 3) + ((reg >> 2) << 3) + rbase;
        // q00: i=ii, j=jc (strict upper triangle)
        if (ii < jc) ob[ii * 63 - ((ii * (ii - 1)) >> 1) + (jc - ii - 1)] = a00[reg];
        // q01: i=ii, j=32+jc (always i<j)
        const int j1 = 32 + jc;
        ob[ii * 63 - ((ii * (ii - 1)) >> 1) + (j1 - ii - 1)] = a01[reg];
        // q11: i=32+ii, j=32+jc
        const int i2 = 32 + ii;
        if (i2 < j1) ob[i2 * 63 - ((i2 * (i2 - 1)) >> 1) + (j1 - i2 - 1)] = a11[reg];
    }
}

extern "C" void kernel_launch(void* const* d_in, const int* in_sizes, int n_in,
                              void* d_out, int out_size, void* d_ws, size_t ws_size,
                              hipStream_t stream) {
    const float* x = (const float*)d_in[0];
    float* out = (float*)d_out;
    gram_tri<<<4096 / 4, 256, 0, stream>>>(x, out);
}

// Round 2
// 361.170 us; speedup vs baseline: 1.0295x; 1.0295x over previous
//
#include <hip/hip_runtime.h>

#define FF 64
#define DD 256
#define KC 128            // K-chunk (elements)
#define LSTR 136          // LDS row stride in bf16 elems: 272 B = 17×16 B (odd → conflict-free b128 reads)
#define NPAIR 2016        // 64*63/2
#define ROWS 4            // batch rows per block
#define NCHUNK (2 * ROWS)

typedef __attribute__((ext_vector_type(8))) short short8;
typedef __attribute__((ext_vector_type(16))) float f32x16;

// two fp32 -> packed bf16x2, round-to-nearest-even
__device__ __forceinline__ unsigned int pack2(float lo, float hi) {
    unsigned int a = __float_as_uint(lo);
    unsigned int b = __float_as_uint(hi);
    a += 0x7FFFu + ((a >> 16) & 1u);
    b += 0x7FFFu + ((b >> 16) & 1u);
    return (a >> 16) | (b & 0xFFFF0000u);
}

__global__ __launch_bounds__(256, 4) void gram_tri(const float* __restrict__ x,
                                                   float* __restrict__ out) {
    __shared__ __align__(16) unsigned short sbuf[2][FF * LSTR];  // 2 × 17.4 KB
    const int t = threadIdx.x;
    const int wave = t >> 6;
    const int lane = t & 63;
    const int b0 = blockIdx.x * ROWS;

    const int qi = wave >> 1, qj = wave & 1;   // wave 2 = (1,0) lower quadrant: skipped
    const unsigned short* ldsA0 = &sbuf[0][(qi * 32 + (lane & 31)) * LSTR + ((lane >> 5) << 3)];
    const unsigned short* ldsB0 = &sbuf[0][(qj * 32 + (lane & 31)) * LSTR + ((lane >> 5) << 3)];
    const int bufoff = FF * LSTR;

    float4 sr[8];
    f32x16 acc;

    // ---- prologue: stage chunk 0 into buf 0 ----
    {
        const float4* __restrict__ src = (const float4*)(x + (size_t)b0 * (FF * DD));
#pragma unroll
        for (int it = 0; it < 8; ++it) {
            int lin = (it << 8) + t;                       // 0..2047
            sr[it] = src[((lin >> 5) << 6) + (lin & 31)];  // f*64 + kq (float4 units)
        }
#pragma unroll
        for (int it = 0; it < 8; ++it) {
            int lin = (it << 8) + t;
            int f = lin >> 5, kq = lin & 31;
            uint2 w;
            w.x = pack2(sr[it].x, sr[it].y);
            w.y = pack2(sr[it].z, sr[it].w);
            *(uint2*)&sbuf[0][f * LSTR + (kq << 2)] = w;
        }
    }
    __syncthreads();

#pragma unroll
    for (int s = 0; s < NCHUNK; ++s) {
        // 1) issue next chunk's global loads (stay in flight across MFMA)
        if (s + 1 < NCHUNK) {
            int nb = b0 + ((s + 1) >> 1);
            int kc = ((s + 1) & 1) * KC;
            const float4* __restrict__ src = (const float4*)(x + (size_t)nb * (FF * DD) + kc);
#pragma unroll
            for (int it = 0; it < 8; ++it) {
                int lin = (it << 8) + t;
                sr[it] = src[((lin >> 5) << 6) + (lin & 31)];
            }
        }
        // 2) MFMA on current buffer
        if ((s & 1) == 0) {
#pragma unroll
            for (int i = 0; i < 16; ++i) acc[i] = 0.0f;
        }
        if (wave != 2) {
            const unsigned short* pA = ldsA0 + (s & 1) * bufoff;
            const unsigned short* pB = ldsB0 + (s & 1) * bufoff;
#pragma unroll
            for (int ko = 0; ko < KC; ko += 16) {
                short8 a  = *(const short8*)(pA + ko);   // 16B-aligned ds_read_b128, conflict-free
                short8 bb = *(const short8*)(pB + ko);
                acc = __builtin_amdgcn_mfma_f32_32x32x16_bf16(a, bb, acc, 0, 0, 0);
            }
        }
        // 3) convert + write next chunk into the other buffer
        if (s + 1 < NCHUNK) {
            unsigned short* dst = &sbuf[0][((s + 1) & 1) * bufoff];
#pragma unroll
            for (int it = 0; it < 8; ++it) {
                int lin = (it << 8) + t;
                int f = lin >> 5, kq = lin & 31;
                uint2 w;
                w.x = pack2(sr[it].x, sr[it].y);
                w.y = pack2(sr[it].z, sr[it].w);
                *(uint2*)&dst[f * LSTR + (kq << 2)] = w;
            }
        }
        __syncthreads();
        // 4) epilogue after a row's second chunk (reads only registers)
        if ((s & 1) && wave != 2) {
            int b = b0 + (s >> 1);
            float* __restrict__ ob = out + (size_t)b * NPAIR;
#pragma unroll
            for (int reg = 0; reg < 16; ++reg) {
                // C/D layout (m74/m101): col=lane&31, row=(reg&3)+8*(reg>>2)+4*(lane>>5)
                int i = (qi << 5) + (reg & 3) + ((reg >> 2) << 3) + ((lane >> 5) << 2);
                int j = (qj << 5) + (lane & 31);
                if (i < j) ob[i * 63 - ((i * (i - 1)) >> 1) + (j - i - 1)] = acc[reg];
            }
        }
    }
}

extern "C" void kernel_launch(void* const* d_in, const int* in_sizes, int n_in,
                              void* d_out, int out_size, void* d_ws, size_t ws_size,
                              hipStream_t stream) {
    const float* x = (const float*)d_in[0];
    float* out = (float*)d_out;
    gram_tri<<<4096 / ROWS, 256, 0, stream>>>(x, out);
}